// Round 2
// baseline (18714.091 us; speedup 1.0000x reference)
//
#include <hip/hip_runtime.h>

typedef unsigned short u16;
typedef __attribute__((ext_vector_type(8))) short bfrag;
typedef __attribute__((ext_vector_type(4))) float f32x4;

#define MFMA __builtin_amdgcn_mfma_f32_16x16x32_bf16

// ---------------- ws layout (bytes) ----------------
#define OFF_FLAGS 0ull           //  1024   (int[256])
#define OFF_HENC  1024ull        //  524288 ([2][512][256] bf16)  <- memset w/ flags
#define OFF_WENC  525312ull      //  589824
#define OFF_WDEC  1115136ull     //  2752512
#define OFF_WY    3867648ull     //  139264
#define OFF_WMS   4006912ull     //  278528 ([256][544] bf16)
#define OFF_WH0   4285440ull     //  163840 ([512][160] bf16)
#define OFF_HDEC  4449280ull     //  1048576 ([2][512][512] bf16)
#define OFF_HLAT  5497856ull     //  557056 ([512][544] bf16)
#define OFF_MS    6054912ull     //  524288 ([512][256] f32)
#define OFF_AZ    6579200ull     //  163840 ([512][160] bf16)

__device__ __forceinline__ u16 f2bf(float f) {
  union { float f; unsigned int i; } v; v.f = f;
  unsigned int r = v.i + 0x7fffu + ((v.i >> 16) & 1u);
  return (u16)(r >> 16);
}
__device__ __forceinline__ float sigm(float x) { return 1.0f / (1.0f + __expf(-x)); }
__device__ __forceinline__ float tanh_(float x) {
  float a = fabsf(x);
  float e = __expf(-2.0f * a);
  float r = (1.0f - e) / (1.0f + e);
  return x < 0.0f ? -r : r;
}

__device__ __forceinline__ void bar_wait(int* flags, int ep, int tid) {
  if (ep > 0) {
    int spin = 0;
    while (__hip_atomic_load(&flags[tid], __ATOMIC_ACQUIRE, __HIP_MEMORY_SCOPE_AGENT) < ep) {
      __builtin_amdgcn_s_sleep(2);
      if (++spin > (1 << 16)) break;   // fail loud (wrong answer), never hang
    }
  }
  __syncthreads();
}
__device__ __forceinline__ void bar_arrive(int* flags, int blk, int ep, int tid) {
  __syncthreads();   // drains each wave's vmem before barrier (HIP semantics)
  if (tid == 0)
    __hip_atomic_store(&flags[blk], ep, __ATOMIC_RELEASE, __HIP_MEMORY_SCOPE_AGENT);
}

// ============================================================= prep packs
__global__ void pack_wenc(const float* __restrict__ Whh, const float* __restrict__ Wih,
                          const float* __restrict__ bi, const float* __restrict__ bh,
                          u16* __restrict__ out) {
  int idx = blockIdx.x * 256 + threadIdx.x;
  if (idx >= 294912) return;
  int bn = idx / 9216, within = idx % 9216;
  int kb = within >> 10, rest = within & 1023;
  int ng = rest >> 9, l = (rest >> 3) & 63, j = rest & 7;
  int nl = ng * 16 + (l & 15);
  int u = nl >> 2, g = nl & 3;
  int row = g * 256 + bn * 8 + u;
  int k = kb * 32 + (l >> 4) * 8 + j;
  float v = 0.f;
  if (k < 256) v = Whh[row * 256 + k];
  else if (k < 261) v = Wih[row * 5 + (k - 256)];
  else if (k == 261) v = bi[row] + bh[row];
  out[idx] = f2bf(v);
}

__global__ void pack_wdec(const float* __restrict__ Whh, const float* __restrict__ Wih,
                          const float* __restrict__ bi, const float* __restrict__ bh,
                          u16* __restrict__ out) {
  int idx = blockIdx.x * 256 + threadIdx.x;
  if (idx >= 1376256) return;
  int bn = idx / 43008, within = idx % 43008;
  int kb = within >> 11, rest = within & 2047;
  int w = rest >> 9, l = (rest >> 3) & 63, j = rest & 7;
  int nl = w * 16 + (l & 15);
  int u = nl >> 2, g = nl & 3;
  int row = g * 512 + bn * 16 + u;
  int k = kb * 32 + (l >> 4) * 8 + j;
  float v = 0.f;
  if (k < 512) v = Whh[row * 512 + k];            // h
  else if (k < 640) v = Wih[row * 133 + 5 + (k - 512)];  // z
  else if (k < 645) v = Wih[row * 133 + (k - 640)];      // x
  else if (k == 645) v = bi[row] + bh[row];
  out[idx] = f2bf(v);
}

__global__ void pack_wy(const float* __restrict__ Wd, u16* __restrict__ out) {
  int idx = blockIdx.x * 256 + threadIdx.x;
  if (idx >= 65536) return;
  int bnY = idx >> 13, within = idx & 8191;
  int kb = within >> 9, rest = within & 511;
  int l = rest >> 3, j = rest & 7;
  int row = bnY * 16 + (l & 15);
  int k = kb * 32 + (l >> 4) * 8 + j;
  float v = (row < 123 && k < 512) ? Wd[row * 512 + k] : 0.f;
  out[idx] = f2bf(v);
}

__global__ void pack_wms(const float* __restrict__ Wmu, const float* __restrict__ bmu,
                         const float* __restrict__ Wsig, const float* __restrict__ bsig,
                         u16* __restrict__ out) {
  int idx = blockIdx.x * 256 + threadIdx.x;
  if (idx >= 139264) return;
  int r = idx / 544, k = idx % 544;
  float v = 0.f;
  if (r < 128) {
    if (k < 512) v = Wmu[r * 512 + k];
    else if (k == 512) v = bmu[r];
  } else {
    int r2 = r - 128;
    if (k < 512) v = Wsig[r2 * 512 + k];
    else if (k == 512) v = bsig[r2];
  }
  out[idx] = f2bf(v);
}

__global__ void pack_wh0(const float* __restrict__ Wh0, const float* __restrict__ bh0,
                         u16* __restrict__ out) {
  int idx = blockIdx.x * 256 + threadIdx.x;
  if (idx >= 81920) return;
  int r = idx / 160, k = idx % 160;
  float v = 0.f;
  if (k < 128) v = Wh0[r * 128 + k];
  else if (k == 128) v = bh0[r];
  out[idx] = f2bf(v);
}

// ============================================================= persistent
__global__ __launch_bounds__(256, 1) void rnn_persist(
    int* __restrict__ flags, u16* __restrict__ henc,
    const u16* __restrict__ WENCP, const u16* __restrict__ WDECP,
    const u16* __restrict__ WYP, const u16* __restrict__ WMSP, const u16* __restrict__ WH0P,
    u16* __restrict__ hdec, u16* __restrict__ hlat, float* __restrict__ msbuf,
    u16* __restrict__ Az,
    const float* __restrict__ s, const float* __restrict__ eps,
    const float* __restrict__ Wih_b, const float* __restrict__ bih_b,
    const float* __restrict__ bhh_b,
    const float* __restrict__ b_dec, float* __restrict__ out)
{
  // LDS: A-tile [32][680] u16 (21760) | gate weights (43008) | y weights (8192)
  __shared__ __align__(16) u16 sm[72960];
  __shared__ __align__(16) float gbuf[2112];   // [32][66] f32

  const int tid = threadIdx.x;
  const int blk = blockIdx.x;
  const int w = tid >> 6, l = tid & 63;
  const int lr = l & 15, ko = (l >> 4) * 8;
  const int bm = blk >> 5, bn = blk & 31;
  const bool yblk = (bn < 8);

  float* out_mu = out + 16121856;
  float* out_ps = out + 16187392;

  // zero A region (keeps pad cols finite; weights there are zero)
  {
    bfrag zz = {0, 0, 0, 0, 0, 0, 0, 0};
    #pragma unroll
    for (int i = 0; i < 11; ++i) {
      int c = i * 256 + tid;
      if (c < 2720) *(bfrag*)(sm + c * 8) = zz;
    }
  }
  // load encoder weight slice (9216 u16)
  {
    const u16* src = WENCP + (size_t)bn * 9216;
    #pragma unroll
    for (int i = 0; i < 5; ++i) {
      int c = i * 256 + tid;
      if (c < 1152) *(bfrag*)(sm + 21760 + c * 8) = *(const bfrag*)(src + c * 8);
    }
  }
  __syncthreads();

  // ---------------- encoder: 256 steps x 2 batch-halves ----------------
  float c_enc[2] = {0.f, 0.f};
  #pragma unroll 1
  for (int t = 0; t < 256; ++t) {
    #pragma unroll
    for (int h = 0; h < 2; ++h) {
      bar_wait(flags, 2 * t + h - 1, tid);
      {  // stage h(t-1) rows of this half: 16KB
        const u16* src = henc + (size_t)((t - 1) & 1) * 131072 + (size_t)(bm * 64 + h * 32) * 256;
        #pragma unroll
        for (int i = 0; i < 4; ++i) {
          int c = i * 256 + tid;
          int row = c >> 5, col = (c & 31) * 8;
          *(bfrag*)(sm + row * 296 + col) = *(const bfrag*)(src + c * 8);
        }
      }
      if (tid < 32) {
        int b = bm * 64 + h * 32 + tid;
        #pragma unroll
        for (int j = 0; j < 5; ++j)
          sm[tid * 296 + 256 + j] = f2bf(s[((size_t)b * 256 + t) * 5 + j]);
        sm[tid * 296 + 261] = 0x3F80;
      }
      __syncthreads();
      const int mt = w >> 1, ng = w & 1;
      f32x4 acc = {0.f, 0.f, 0.f, 0.f};
      #pragma unroll
      for (int kb = 0; kb < 9; ++kb) {
        bfrag a = *(const bfrag*)(sm + (mt * 16 + lr) * 296 + kb * 32 + ko);
        bfrag bw = *(const bfrag*)(sm + 21760 + (kb * 2 + ng) * 512 + l * 8);
        acc = MFMA(a, bw, acc, 0, 0, 0);
      }
      #pragma unroll
      for (int j = 0; j < 4; ++j)
        gbuf[(mt * 16 + (l >> 4) * 4 + j) * 33 + ng * 16 + lr] = acc[j];
      __syncthreads();
      {
        int bl = tid >> 3, u = tid & 7;
        float gi = gbuf[bl * 33 + u * 4 + 0], gf = gbuf[bl * 33 + u * 4 + 1];
        float gg = gbuf[bl * 33 + u * 4 + 2], go = gbuf[bl * 33 + u * 4 + 3];
        float c = sigm(gf) * c_enc[h] + sigm(gi) * tanh_(gg);
        c_enc[h] = c;
        float hh = sigm(go) * tanh_(c);
        henc[(size_t)(t & 1) * 131072 + (size_t)(bm * 64 + h * 32 + bl) * 256 + bn * 8 + u] = f2bf(hh);
      }
      bar_arrive(flags, blk, 2 * t + h + 1, tid);
    }
  }

  // ---------------- latent ----------------
  bar_wait(flags, 512, tid);
  {  // load decoder gate weights into LDS (overlaps latent math)
    const u16* src = WDECP + (size_t)bn * 43008;
    #pragma unroll 1
    for (int i = 0; i < 21; ++i) {
      int c = i * 256 + tid;
      *(bfrag*)(sm + 21760 + c * 8) = *(const bfrag*)(src + c * 8);
    }
  }
  if (yblk) {
    const u16* src = WYP + (size_t)bn * 8192;
    #pragma unroll
    for (int i = 0; i < 4; ++i) {
      int c = i * 256 + tid;
      *(bfrag*)(sm + 64768 + c * 8) = *(const bfrag*)(src + c * 8);
    }
  }
  // Lphase A: backward-LSTM single step + hlat = [hf | hb | 1 | 0]
  #pragma unroll
  for (int r = 0; r < 2; ++r) {
    int b = blk * 2 + r;
    const float* xr = s + ((size_t)b * 256 + 255) * 5;
    float x0 = xr[0], x1 = xr[1], x2 = xr[2], x3 = xr[3], x4 = xr[4];
    int n = tid;
    float gv[4];
    #pragma unroll
    for (int g = 0; g < 4; ++g) {
      int row = g * 256 + n;
      gv[g] = bih_b[row] + bhh_b[row] + x0 * Wih_b[row * 5] + x1 * Wih_b[row * 5 + 1] +
              x2 * Wih_b[row * 5 + 2] + x3 * Wih_b[row * 5 + 3] + x4 * Wih_b[row * 5 + 4];
    }
    float c = sigm(gv[0]) * tanh_(gv[2]);
    float hb = sigm(gv[3]) * tanh_(c);
    hlat[(size_t)b * 544 + 256 + n] = f2bf(hb);
    hlat[(size_t)b * 544 + n] = henc[131072 + (size_t)b * 256 + n];
    if (n == 0) hlat[(size_t)b * 544 + 512] = 0x3F80;
    if (n < 31) hlat[(size_t)b * 544 + 513 + n] = 0;
  }
  bar_arrive(flags, blk, 513, tid);
  bar_wait(flags, 513, tid);
  // Lphase B: [mu|presig] = hlat @ WMS^T   (waves 0,1)
  {
    const int bmL = blk >> 4, bnL = blk & 15;
    if (w < 2) {
      const int mt = w;
      f32x4 acc = {0.f, 0.f, 0.f, 0.f};
      const u16* ap = hlat + (size_t)(bmL * 32 + mt * 16 + lr) * 544 + ko;
      const u16* bp = WMSP + (size_t)(bnL * 16 + lr) * 544 + ko;
      #pragma unroll
      for (int kb = 0; kb < 17; ++kb) {
        bfrag a = *(const bfrag*)(ap + kb * 32);
        bfrag bb = *(const bfrag*)(bp + kb * 32);
        acc = MFMA(a, bb, acc, 0, 0, 0);
      }
      int nc = bnL * 16 + lr;
      #pragma unroll
      for (int j = 0; j < 4; ++j) {
        int b = bmL * 32 + mt * 16 + (l >> 4) * 4 + j;
        msbuf[(size_t)b * 256 + nc] = acc[j];
        if (nc < 128) out_mu[(size_t)b * 128 + nc] = acc[j];
        else out_ps[(size_t)b * 128 + nc - 128] = acc[j];
      }
    }
  }
  bar_arrive(flags, blk, 514, tid);
  bar_wait(flags, 514, tid);
  // Lphase C: z = mu + exp(ps/2)*eps -> Az = [z | 1 | 0]
  {
    int idx = blk * 256 + tid;
    int b = idx >> 7, zj = idx & 127;
    float mu = msbuf[(size_t)b * 256 + zj], ps = msbuf[(size_t)b * 256 + 128 + zj];
    float z = mu + __expf(0.5f * ps) * eps[zj];
    Az[(size_t)b * 160 + zj] = f2bf(z);
    if (zj == 0) Az[(size_t)b * 160 + 128] = 0x3F80;
    if (zj < 31) Az[(size_t)b * 160 + 129 + zj] = 0;
  }
  bar_arrive(flags, blk, 515, tid);
  bar_wait(flags, 515, tid);
  // Lphase D: h0 = tanh(Az @ WH0^T) -> hdec[1]
  {
    const int bmL = blk >> 4, bnL = blk & 15;
    const int mt = w >> 1, ng = w & 1;
    f32x4 acc = {0.f, 0.f, 0.f, 0.f};
    const u16* ap = Az + (size_t)(bmL * 32 + mt * 16 + lr) * 160 + ko;
    const u16* bp = WH0P + (size_t)(bnL * 32 + ng * 16 + lr) * 160 + ko;
    #pragma unroll
    for (int kb = 0; kb < 5; ++kb) {
      bfrag a = *(const bfrag*)(ap + kb * 32);
      bfrag bb = *(const bfrag*)(bp + kb * 32);
      acc = MFMA(a, bb, acc, 0, 0, 0);
    }
    #pragma unroll
    for (int j = 0; j < 4; ++j) {
      int b = bmL * 32 + mt * 16 + (l >> 4) * 4 + j;
      hdec[262144 + (size_t)b * 512 + bnL * 32 + ng * 16 + lr] = f2bf(tanh_(acc[j]));
    }
  }
  bar_arrive(flags, blk, 516, tid);
  bar_wait(flags, 516, tid);

  // ---------------- decoder: 256 steps x 2 halves + fused y ----------------
  float c_dec[4] = {0.f, 0.f, 0.f, 0.f};
  #pragma unroll 1
  for (int t = 0; t < 256; ++t) {
    #pragma unroll
    for (int h = 0; h < 2; ++h) {
      {
        int tg = 2 * t + h;
        bar_wait(flags, 516 + (tg == 0 ? 0 : tg - 1), tid);
      }
      {  // stage h(t-1): 32KB
        const u16* src = hdec + (size_t)((t - 1) & 1) * 262144 + (size_t)(bm * 64 + h * 32) * 512;
        #pragma unroll
        for (int i = 0; i < 8; ++i) {
          int c = i * 256 + tid;
          int row = c >> 6, col = (c & 63) * 8;
          *(bfrag*)(sm + row * 680 + col) = *(const bfrag*)(src + c * 8);
        }
      }
      {  // stage z: cols 512..639
        #pragma unroll
        for (int i = 0; i < 2; ++i) {
          int c = i * 256 + tid;
          int row = c >> 4, colz = (c & 15) * 8;
          *(bfrag*)(sm + row * 680 + 512 + colz) =
              *(const bfrag*)(Az + (size_t)(bm * 64 + h * 32 + row) * 160 + colz);
        }
      }
      if (tid < 32) {  // x cols 640..644, bias col 645
        int b = bm * 64 + h * 32 + tid;
        if (t == 0) {
          sm[tid * 680 + 640] = 0; sm[tid * 680 + 641] = 0; sm[tid * 680 + 642] = 0x3F80;
          sm[tid * 680 + 643] = 0; sm[tid * 680 + 644] = 0;
        } else {
          #pragma unroll
          for (int j = 0; j < 5; ++j)
            sm[tid * 680 + 640 + j] = f2bf(s[((size_t)b * 256 + (t - 1)) * 5 + j]);
        }
        sm[tid * 680 + 645] = 0x3F80;
      }
      __syncthreads();
      const bool doy = yblk && (w < 2) && (t > 0);
      f32x4 acc0 = {0.f, 0.f, 0.f, 0.f}, acc1 = {0.f, 0.f, 0.f, 0.f}, accy = {0.f, 0.f, 0.f, 0.f};
      #pragma unroll
      for (int kb = 0; kb < 21; ++kb) {
        bfrag a0 = *(const bfrag*)(sm + lr * 680 + kb * 32 + ko);
        bfrag a1 = *(const bfrag*)(sm + (16 + lr) * 680 + kb * 32 + ko);
        bfrag bw = *(const bfrag*)(sm + 21760 + kb * 2048 + w * 512 + l * 8);
        acc0 = MFMA(a0, bw, acc0, 0, 0, 0);
        acc1 = MFMA(a1, bw, acc1, 0, 0, 0);
        if (kb < 16 && doy) {
          bfrag by = *(const bfrag*)(sm + 64768 + kb * 512 + l * 8);
          accy = MFMA(w == 0 ? a0 : a1, by, accy, 0, 0, 0);
        }
      }
      if (doy) {  // y_{t-1} raw -> d_out (MDN applied later in place)
        int gcol = bn * 16 + lr;
        if (gcol < 123) {
          float bd = b_dec[gcol];
          int brow = bm * 64 + h * 32 + w * 16 + (l >> 4) * 4;
          #pragma unroll
          for (int j = 0; j < 4; ++j)
            out[((size_t)(brow + j) * 256 + (t - 1)) * 123 + gcol] = accy[j] + bd;
        }
      }
      #pragma unroll
      for (int j = 0; j < 4; ++j) {
        gbuf[((l >> 4) * 4 + j) * 66 + w * 16 + lr] = acc0[j];
        gbuf[(16 + (l >> 4) * 4 + j) * 66 + w * 16 + lr] = acc1[j];
      }
      __syncthreads();
      #pragma unroll
      for (int p = 0; p < 2; ++p) {
        int idx = p * 256 + tid;
        int bl = idx >> 4, u = idx & 15;
        float gi = gbuf[bl * 66 + u * 4 + 0], gf = gbuf[bl * 66 + u * 4 + 1];
        float gg = gbuf[bl * 66 + u * 4 + 2], go = gbuf[bl * 66 + u * 4 + 3];
        float c = sigm(gf) * c_dec[h * 2 + p] + sigm(gi) * tanh_(gg);
        c_dec[h * 2 + p] = c;
        float hh = sigm(go) * tanh_(c);
        hdec[(size_t)(t & 1) * 262144 + (size_t)(bm * 64 + h * 32 + bl) * 512 + bn * 16 + u] = f2bf(hh);
      }
      bar_arrive(flags, blk, 517 + 2 * t + h, tid);
    }
  }
  // extra step: y_255 from h(255) (hdec[1])
  #pragma unroll
  for (int h = 0; h < 2; ++h) {
    bar_wait(flags, 1027 + h, tid);
    {
      const u16* src = hdec + 262144 + (size_t)(bm * 64 + h * 32) * 512;
      #pragma unroll
      for (int i = 0; i < 8; ++i) {
        int c = i * 256 + tid;
        int row = c >> 6, col = (c & 63) * 8;
        *(bfrag*)(sm + row * 680 + col) = *(const bfrag*)(src + c * 8);
      }
    }
    __syncthreads();
    if (yblk && w < 2) {
      f32x4 accy = {0.f, 0.f, 0.f, 0.f};
      #pragma unroll
      for (int kb = 0; kb < 16; ++kb) {
        bfrag a = *(const bfrag*)(sm + ((w ? 16 : 0) + lr) * 680 + kb * 32 + ko);
        bfrag by = *(const bfrag*)(sm + 64768 + kb * 512 + l * 8);
        accy = MFMA(a, by, accy, 0, 0, 0);
      }
      int gcol = bn * 16 + lr;
      if (gcol < 123) {
        float bd = b_dec[gcol];
        int brow = bm * 64 + h * 32 + w * 16 + (l >> 4) * 4;
        #pragma unroll
        for (int j = 0; j < 4; ++j)
          out[((size_t)(brow + j) * 256 + 255) * 123 + gcol] = accy[j] + bd;
      }
    }
    __syncthreads();
  }
}

// ============================================================= MDN in place
__global__ __launch_bounds__(64) void mdn_final(float* __restrict__ out) {
  __shared__ float rows[64 * 123];
  const int tid = threadIdx.x;
  float4* g4 = (float4*)(out + (size_t)blockIdx.x * 64 * 123);
  #pragma unroll
  for (int i = 0; i < 31; ++i) {
    int c = i * 64 + tid;
    if (c < 1968) ((float4*)rows)[c] = g4[c];
  }
  __syncthreads();
  {
    float* r = rows + tid * 123;
    float m1 = -1e30f;
    #pragma unroll
    for (int k = 0; k < 20; ++k) m1 = fmaxf(m1, r[6 * k]);
    float s1 = 0.f;
    #pragma unroll
    for (int k = 0; k < 20; ++k) s1 += __expf(r[6 * k] - m1);
    float i1 = 1.f / s1;
    #pragma unroll
    for (int k = 0; k < 20; ++k) {
      r[6 * k] = __expf(r[6 * k] - m1) * i1;
      r[6 * k + 3] = __expf(r[6 * k + 3]);
      r[6 * k + 4] = __expf(r[6 * k + 4]);
      r[6 * k + 5] = tanh_(r[6 * k + 5]);
    }
    float p0 = r[120], p1 = r[121], p2 = r[122];
    float mp = fmaxf(p0, fmaxf(p1, p2));
    float e0 = __expf(p0 - mp), e1 = __expf(p1 - mp), e2 = __expf(p2 - mp);
    float ip = 1.f / (e0 + e1 + e2);
    r[120] = e0 * ip; r[121] = e1 * ip; r[122] = e2 * ip;
  }
  __syncthreads();
  #pragma unroll
  for (int i = 0; i < 31; ++i) {
    int c = i * 64 + tid;
    if (c < 1968) g4[c] = ((float4*)rows)[c];
  }
}

extern "C" void kernel_launch(void* const* d_in, const int* in_sizes, int n_in,
                              void* d_out, int out_size, void* d_ws, size_t ws_size,
                              hipStream_t stream) {
  const float* s       = (const float*)d_in[0];
  const float* eps     = (const float*)d_in[1];
  const float* Wih_f   = (const float*)d_in[2];
  const float* Whh_f   = (const float*)d_in[3];
  const float* bih_f   = (const float*)d_in[4];
  const float* bhh_f   = (const float*)d_in[5];
  const float* Wih_b   = (const float*)d_in[6];
  const float* bih_b   = (const float*)d_in[8];
  const float* bhh_b   = (const float*)d_in[9];
  const float* W_sigma = (const float*)d_in[10];
  const float* b_sigma = (const float*)d_in[11];
  const float* W_mu    = (const float*)d_in[12];
  const float* b_mu    = (const float*)d_in[13];
  const float* W_h0    = (const float*)d_in[14];
  const float* b_h0    = (const float*)d_in[15];
  const float* Wih_d   = (const float*)d_in[16];
  const float* Whh_d   = (const float*)d_in[17];
  const float* bih_d   = (const float*)d_in[18];
  const float* bhh_d   = (const float*)d_in[19];
  const float* W_dec   = (const float*)d_in[20];
  const float* b_dec   = (const float*)d_in[21];

  char* ws = (char*)d_ws;
  int* FLAGS  = (int*)(ws + OFF_FLAGS);
  u16* HENC   = (u16*)(ws + OFF_HENC);
  u16* WENCP  = (u16*)(ws + OFF_WENC);
  u16* WDECP  = (u16*)(ws + OFF_WDEC);
  u16* WYP    = (u16*)(ws + OFF_WY);
  u16* WMSP   = (u16*)(ws + OFF_WMS);
  u16* WH0P   = (u16*)(ws + OFF_WH0);
  u16* HDEC   = (u16*)(ws + OFF_HDEC);
  u16* HLAT   = (u16*)(ws + OFF_HLAT);
  float* MS   = (float*)(ws + OFF_MS);
  u16* AZ     = (u16*)(ws + OFF_AZ);
  float* out  = (float*)d_out;

  // reset barrier flags + zero encoder h(-1) every launch (graph-replay safe)
  hipMemsetAsync(ws, 0, 1024 + 524288, stream);

  pack_wenc<<<1152, 256, 0, stream>>>(Whh_f, Wih_f, bih_f, bhh_f, WENCP);
  pack_wdec<<<5376, 256, 0, stream>>>(Whh_d, Wih_d, bih_d, bhh_d, WDECP);
  pack_wy<<<256, 256, 0, stream>>>(W_dec, WYP);
  pack_wms<<<544, 256, 0, stream>>>(W_mu, b_mu, W_sigma, b_sigma, WMSP);
  pack_wh0<<<320, 256, 0, stream>>>(W_h0, b_h0, WH0P);

  rnn_persist<<<256, 256, 0, stream>>>(FLAGS, HENC, WENCP, WDECP, WYP, WMSP, WH0P,
                                       HDEC, HLAT, MS, AZ, s, eps,
                                       Wih_b, bih_b, bhh_b, b_dec, out);

  mdn_final<<<2048, 64, 0, stream>>>(out);

  (void)in_sizes; (void)n_in; (void)out_size; (void)ws_size;
}

// Round 3
// 12829.669 us; speedup vs baseline: 1.4587x; 1.4587x over previous
//
#include <hip/hip_runtime.h>

typedef unsigned short u16;
typedef __attribute__((ext_vector_type(8))) short bfrag;
typedef __attribute__((ext_vector_type(4))) float f32x4;

#define MFMA __builtin_amdgcn_mfma_f32_16x16x32_bf16

// ---------------- ws layout (bytes) ----------------
#define OFF_FLAGS 0ull           //  4096 (8 groups x 64 ints, 256B stride)
#define OFF_HENC  4096ull        //  524288 ([2][512][256] bf16)  <- memset w/ flags
#define OFF_WENC  528384ull      //  589824
#define OFF_WDEC  1118208ull     //  2752512
#define OFF_WY    3870720ull     //  131072
#define OFF_WMS   4001792ull     //  278528 ([256][544] bf16)
#define OFF_WH0   4280320ull     //  163840 ([512][160] bf16)
#define OFF_HDEC  4444160ull     //  1048576 ([2][512][512] bf16)
#define OFF_HLAT  5492736ull     //  557056 ([512][544] bf16)
#define OFF_MS    6049792ull     //  524288 ([512][256] f32)
#define OFF_AZ    6574080ull     //  163840 ([512][160] bf16)

__device__ __forceinline__ u16 f2bf(float f) {
  union { float f; unsigned int i; } v; v.f = f;
  unsigned int r = v.i + 0x7fffu + ((v.i >> 16) & 1u);
  return (u16)(r >> 16);
}
__device__ __forceinline__ float sigm(float x) { return 1.0f / (1.0f + __expf(-x)); }
__device__ __forceinline__ float tanh_(float x) {
  float a = fabsf(x);
  float e = __expf(-2.0f * a);
  float r = (1.0f - e) / (1.0f + e);
  return x < 0.0f ? -r : r;
}

// group barrier: 32 blocks of group g. One wave polls 32 flags (2 cache lines).
__device__ __forceinline__ void gbar_wait(int* flags, int g, int ep, int tid, int* sdead) {
  if (ep > 0) {
    if (*sdead == 0 && tid < 32) {
      int* fp = flags + g * 64 + tid;
      int spin = 0;
      while (__hip_atomic_load(fp, __ATOMIC_RELAXED, __HIP_MEMORY_SCOPE_AGENT) < ep) {
        __builtin_amdgcn_s_sleep(1);
        if (++spin > (1 << 18)) { *sdead = 1; break; }   // fail loud, never hang
      }
      __threadfence();   // acquire: order subsequent data loads after flag observation
    }
  }
  __syncthreads();
}
__device__ __forceinline__ void gbar_arrive(int* flags, int g, int m, int ep, int tid) {
  __syncthreads();   // all waves drain vmem (vmcnt(0)) before tid0 releases
  if (tid == 0)
    __hip_atomic_store(flags + g * 64 + m, ep, __ATOMIC_RELEASE, __HIP_MEMORY_SCOPE_AGENT);
}

// ============================================================= prep packs
__global__ void pack_wenc(const float* __restrict__ Whh, const float* __restrict__ Wih,
                          const float* __restrict__ bi, const float* __restrict__ bh,
                          u16* __restrict__ out) {
  int idx = blockIdx.x * 256 + threadIdx.x;
  if (idx >= 294912) return;
  int m = idx / 9216, within = idx % 9216;
  int kb = within >> 10, rest = within & 1023;
  int ng = rest >> 9, l = (rest >> 3) & 63, j = rest & 7;
  int nl = ng * 16 + (l & 15);
  int u = nl >> 2, g = nl & 3;
  int row = g * 256 + m * 8 + u;
  int k = kb * 32 + (l >> 4) * 8 + j;
  float v = 0.f;
  if (k < 256) v = Whh[row * 256 + k];
  else if (k < 261) v = Wih[row * 5 + (k - 256)];
  else if (k == 261) v = bi[row] + bh[row];
  out[idx] = f2bf(v);
}

__global__ void pack_wdec(const float* __restrict__ Whh, const float* __restrict__ Wih,
                          const float* __restrict__ bi, const float* __restrict__ bh,
                          u16* __restrict__ out) {
  int idx = blockIdx.x * 256 + threadIdx.x;
  if (idx >= 1376256) return;
  int m = idx / 43008, within = idx % 43008;
  int kb = within >> 11, rest = within & 2047;
  int w = rest >> 9, l = (rest >> 3) & 63, j = rest & 7;
  int nl = w * 16 + (l & 15);
  int u = nl >> 2, g = nl & 3;
  int row = g * 512 + m * 16 + u;
  int k = kb * 32 + (l >> 4) * 8 + j;
  float v = 0.f;
  if (k < 512) v = Whh[row * 512 + k];                    // h
  else if (k < 640) v = Wih[row * 133 + 5 + (k - 512)];   // z
  else if (k < 645) v = Wih[row * 133 + (k - 640)];       // x
  else if (k == 645) v = bi[row] + bh[row];
  out[idx] = f2bf(v);
}

__global__ void pack_wy(const float* __restrict__ Wd, u16* __restrict__ out) {
  int idx = blockIdx.x * 256 + threadIdx.x;
  if (idx >= 65536) return;
  int m = idx >> 13, within = idx & 8191;
  int kb = within >> 9, rest = within & 511;
  int l = rest >> 3, j = rest & 7;
  int row = m * 16 + (l & 15);
  int k = kb * 32 + (l >> 4) * 8 + j;
  float v = (row < 123 && k < 512) ? Wd[row * 512 + k] : 0.f;
  out[idx] = f2bf(v);
}

__global__ void pack_wms(const float* __restrict__ Wmu, const float* __restrict__ bmu,
                         const float* __restrict__ Wsig, const float* __restrict__ bsig,
                         u16* __restrict__ out) {
  int idx = blockIdx.x * 256 + threadIdx.x;
  if (idx >= 139264) return;
  int r = idx / 544, k = idx % 544;
  float v = 0.f;
  if (r < 128) {
    if (k < 512) v = Wmu[r * 512 + k];
    else if (k == 512) v = bmu[r];
  } else {
    int r2 = r - 128;
    if (k < 512) v = Wsig[r2 * 512 + k];
    else if (k == 512) v = bsig[r2];
  }
  out[idx] = f2bf(v);
}

__global__ void pack_wh0(const float* __restrict__ Wh0, const float* __restrict__ bh0,
                         u16* __restrict__ out) {
  int idx = blockIdx.x * 256 + threadIdx.x;
  if (idx >= 81920) return;
  int r = idx / 160, k = idx % 160;
  float v = 0.f;
  if (k < 128) v = Wh0[r * 128 + k];
  else if (k == 128) v = bh0[r];
  out[idx] = f2bf(v);
}

// ============================================================= persistent
// group g = blk & 7 (XCD-local), member m = blk >> 3. Group owns batch [g*64, g*64+64).
__global__ __launch_bounds__(256, 1) void rnn_persist(
    int* __restrict__ flags, u16* __restrict__ henc,
    const u16* __restrict__ WENCP, const u16* __restrict__ WDECP,
    const u16* __restrict__ WYP, const u16* __restrict__ WMSP, const u16* __restrict__ WH0P,
    u16* __restrict__ hdec, u16* __restrict__ hlat, float* __restrict__ msbuf,
    u16* __restrict__ Az,
    const float* __restrict__ s, const float* __restrict__ eps,
    const float* __restrict__ Wih_b, const float* __restrict__ bih_b,
    const float* __restrict__ bhh_b,
    const float* __restrict__ b_dec, float* __restrict__ out)
{
  // LDS: A-tile [32][680] u16 (21760) | gate weights (43008 u16) | y weights (8192 u16)
  __shared__ __align__(16) u16 sm[72960];
  __shared__ __align__(16) float gbuf[2112];   // [32][66] f32
  __shared__ int sdead;

  const int tid = threadIdx.x;
  const int blk = blockIdx.x;
  const int g = blk & 7;          // XCD group
  const int m = blk >> 3;         // member within group (0..31)
  const int B0 = g * 64;          // group batch base
  const int w = tid >> 6, l = tid & 63;
  const int lr = l & 15, ko = (l >> 4) * 8;

  float* out_mu = out + 16121856;
  float* out_ps = out + 16187392;

  if (tid == 0) sdead = 0;
  // zero A region (keeps pad cols finite; weights there are zero)
  {
    bfrag zz = {0, 0, 0, 0, 0, 0, 0, 0};
    #pragma unroll
    for (int i = 0; i < 11; ++i) {
      int c = i * 256 + tid;
      if (c < 2720) *(bfrag*)(sm + c * 8) = zz;
    }
  }
  // load encoder weight slice (9216 u16)
  {
    const u16* src = WENCP + (size_t)m * 9216;
    #pragma unroll
    for (int i = 0; i < 5; ++i) {
      int c = i * 256 + tid;
      if (c < 1152) *(bfrag*)(sm + 21760 + c * 8) = *(const bfrag*)(src + c * 8);
    }
  }
  __syncthreads();

  // ---------------- encoder: 256 steps x 2 batch-halves (32 rows each) ----------------
  float c_enc[2] = {0.f, 0.f};
  #pragma unroll 1
  for (int t = 0; t < 256; ++t) {
    #pragma unroll
    for (int h = 0; h < 2; ++h) {
      gbar_wait(flags, g, 2 * t + h - 1, tid, &sdead);
      {  // stage h(t-1) rows of this half: 16KB (group-local in L2)
        const u16* src = henc + (size_t)((t - 1) & 1) * 131072 + (size_t)(B0 + h * 32) * 256;
        #pragma unroll
        for (int i = 0; i < 4; ++i) {
          int c = i * 256 + tid;
          int row = c >> 5, col = (c & 31) * 8;
          *(bfrag*)(sm + row * 296 + col) = *(const bfrag*)(src + c * 8);
        }
      }
      if (tid < 32) {
        int b = B0 + h * 32 + tid;
        #pragma unroll
        for (int j = 0; j < 5; ++j)
          sm[tid * 296 + 256 + j] = f2bf(s[((size_t)b * 256 + t) * 5 + j]);
        sm[tid * 296 + 261] = 0x3F80;
      }
      __syncthreads();
      const int mt = w >> 1, ng = w & 1;
      f32x4 acc = {0.f, 0.f, 0.f, 0.f};
      #pragma unroll
      for (int kb = 0; kb < 9; ++kb) {
        bfrag a = *(const bfrag*)(sm + (mt * 16 + lr) * 296 + kb * 32 + ko);
        bfrag bw = *(const bfrag*)(sm + 21760 + (kb * 2 + ng) * 512 + l * 8);
        acc = MFMA(a, bw, acc, 0, 0, 0);
      }
      #pragma unroll
      for (int j = 0; j < 4; ++j)
        gbuf[(mt * 16 + (l >> 4) * 4 + j) * 33 + ng * 16 + lr] = acc[j];
      __syncthreads();
      {
        int bl = tid >> 3, u = tid & 7;
        float gi = gbuf[bl * 33 + u * 4 + 0], gf = gbuf[bl * 33 + u * 4 + 1];
        float gg = gbuf[bl * 33 + u * 4 + 2], go = gbuf[bl * 33 + u * 4 + 3];
        float c = sigm(gf) * c_enc[h] + sigm(gi) * tanh_(gg);
        c_enc[h] = c;
        float hh = sigm(go) * tanh_(c);
        henc[(size_t)(t & 1) * 131072 + (size_t)(B0 + h * 32 + bl) * 256 + m * 8 + u] = f2bf(hh);
      }
      gbar_arrive(flags, g, m, 2 * t + h + 1, tid);
    }
  }

  // ---------------- latent (all group-local) ----------------
  gbar_wait(flags, g, 512, tid, &sdead);
  {  // load decoder gate weights into LDS (overlaps latent math)
    const u16* src = WDECP + (size_t)m * 43008;
    #pragma unroll 1
    for (int i = 0; i < 21; ++i) {
      int c = i * 256 + tid;
      *(bfrag*)(sm + 21760 + c * 8) = *(const bfrag*)(src + c * 8);
    }
  }
  if (m < 8) {
    const u16* src = WYP + (size_t)m * 8192;
    #pragma unroll
    for (int i = 0; i < 4; ++i) {
      int c = i * 256 + tid;
      *(bfrag*)(sm + 64768 + c * 8) = *(const bfrag*)(src + c * 8);
    }
  }
  // Lphase A: backward-LSTM single step + hlat = [hf | hb | 1 | 0]
  #pragma unroll
  for (int r = 0; r < 2; ++r) {
    int b = B0 + m * 2 + r;
    const float* xr = s + ((size_t)b * 256 + 255) * 5;
    float x0 = xr[0], x1 = xr[1], x2 = xr[2], x3 = xr[3], x4 = xr[4];
    int n = tid;
    float gv[4];
    #pragma unroll
    for (int gg = 0; gg < 4; ++gg) {
      int row = gg * 256 + n;
      gv[gg] = bih_b[row] + bhh_b[row] + x0 * Wih_b[row * 5] + x1 * Wih_b[row * 5 + 1] +
               x2 * Wih_b[row * 5 + 2] + x3 * Wih_b[row * 5 + 3] + x4 * Wih_b[row * 5 + 4];
    }
    float c = sigm(gv[0]) * tanh_(gv[2]);
    float hb = sigm(gv[3]) * tanh_(c);
    hlat[(size_t)b * 544 + 256 + n] = f2bf(hb);
    hlat[(size_t)b * 544 + n] = henc[131072 + (size_t)b * 256 + n];
    if (n == 0) hlat[(size_t)b * 544 + 512] = 0x3F80;
    if (n < 31) hlat[(size_t)b * 544 + 513 + n] = 0;
  }
  gbar_arrive(flags, g, m, 513, tid);
  gbar_wait(flags, g, 513, tid, &sdead);
  // Lphase B: [mu|presig] = hlat @ WMS^T. member m: batch-half m>>4, col-tile m&15.
  {
    const int bH = m >> 4, cT = m & 15;
    if (w < 2) {
      const int mt = w;
      f32x4 acc = {0.f, 0.f, 0.f, 0.f};
      const u16* ap = hlat + (size_t)(B0 + bH * 32 + mt * 16 + lr) * 544 + ko;
      const u16* bp = WMSP + (size_t)(cT * 16 + lr) * 544 + ko;
      #pragma unroll
      for (int kb = 0; kb < 17; ++kb) {
        bfrag a = *(const bfrag*)(ap + kb * 32);
        bfrag bb = *(const bfrag*)(bp + kb * 32);
        acc = MFMA(a, bb, acc, 0, 0, 0);
      }
      int nc = cT * 16 + lr;
      #pragma unroll
      for (int j = 0; j < 4; ++j) {
        int b = B0 + bH * 32 + mt * 16 + (l >> 4) * 4 + j;
        msbuf[(size_t)b * 256 + nc] = acc[j];
        if (nc < 128) out_mu[(size_t)b * 128 + nc] = acc[j];
        else out_ps[(size_t)b * 128 + nc - 128] = acc[j];
      }
    }
  }
  gbar_arrive(flags, g, m, 514, tid);
  gbar_wait(flags, g, 514, tid, &sdead);
  // Lphase C: z = mu + exp(ps/2)*eps -> Az = [z | 1 | 0]
  {
    int local = m * 256 + tid;
    int bL = local >> 7, zj = local & 127;
    int b = B0 + bL;
    float mu = msbuf[(size_t)b * 256 + zj], ps = msbuf[(size_t)b * 256 + 128 + zj];
    float z = mu + __expf(0.5f * ps) * eps[zj];
    Az[(size_t)b * 160 + zj] = f2bf(z);
    if (zj == 0) Az[(size_t)b * 160 + 128] = 0x3F80;
    if (zj < 31) Az[(size_t)b * 160 + 129 + zj] = 0;
  }
  gbar_arrive(flags, g, m, 515, tid);
  gbar_wait(flags, g, 515, tid, &sdead);
  // Lphase D: h0 = tanh(Az @ WH0^T) -> hdec slot 1. member m: units m*16..; wave = batch tile.
  {
    f32x4 acc = {0.f, 0.f, 0.f, 0.f};
    const u16* ap = Az + (size_t)(B0 + w * 16 + lr) * 160 + ko;
    const u16* bp = WH0P + (size_t)(m * 16 + lr) * 160 + ko;
    #pragma unroll
    for (int kb = 0; kb < 5; ++kb) {
      bfrag a = *(const bfrag*)(ap + kb * 32);
      bfrag bb = *(const bfrag*)(bp + kb * 32);
      acc = MFMA(a, bb, acc, 0, 0, 0);
    }
    #pragma unroll
    for (int j = 0; j < 4; ++j) {
      int b = B0 + w * 16 + (l >> 4) * 4 + j;
      hdec[262144 + (size_t)b * 512 + m * 16 + lr] = f2bf(tanh_(acc[j]));
    }
  }
  gbar_arrive(flags, g, m, 516, tid);

  // ---------------- decoder: 256 steps x 2 halves + fused y ----------------
  float c_dec[4] = {0.f, 0.f, 0.f, 0.f};
  #pragma unroll 1
  for (int t = 0; t < 256; ++t) {
    #pragma unroll
    for (int h = 0; h < 2; ++h) {
      {
        int tg = 2 * t + h;
        gbar_wait(flags, g, 516 + (tg == 0 ? 0 : tg - 1), tid, &sdead);
      }
      {  // stage h(t-1): 32KB
        const u16* src = hdec + (size_t)((t - 1) & 1) * 262144 + (size_t)(B0 + h * 32) * 512;
        #pragma unroll
        for (int i = 0; i < 8; ++i) {
          int c = i * 256 + tid;
          int row = c >> 6, col = (c & 63) * 8;
          *(bfrag*)(sm + row * 680 + col) = *(const bfrag*)(src + c * 8);
        }
      }
      {  // stage z: cols 512..639
        #pragma unroll
        for (int i = 0; i < 2; ++i) {
          int c = i * 256 + tid;
          int row = c >> 4, colz = (c & 15) * 8;
          *(bfrag*)(sm + row * 680 + 512 + colz) =
              *(const bfrag*)(Az + (size_t)(B0 + h * 32 + row) * 160 + colz);
        }
      }
      if (tid < 32) {  // x cols 640..644, bias col 645
        int b = B0 + h * 32 + tid;
        if (t == 0) {
          sm[tid * 680 + 640] = 0; sm[tid * 680 + 641] = 0; sm[tid * 680 + 642] = 0x3F80;
          sm[tid * 680 + 643] = 0; sm[tid * 680 + 644] = 0;
        } else {
          #pragma unroll
          for (int j = 0; j < 5; ++j)
            sm[tid * 680 + 640 + j] = f2bf(s[((size_t)b * 256 + (t - 1)) * 5 + j]);
        }
        sm[tid * 680 + 645] = 0x3F80;
      }
      __syncthreads();
      const bool doy = (m < 8) && (w < 2) && (t > 0);
      f32x4 acc0 = {0.f, 0.f, 0.f, 0.f}, acc1 = {0.f, 0.f, 0.f, 0.f}, accy = {0.f, 0.f, 0.f, 0.f};
      #pragma unroll
      for (int kb = 0; kb < 21; ++kb) {
        bfrag a0 = *(const bfrag*)(sm + lr * 680 + kb * 32 + ko);
        bfrag a1 = *(const bfrag*)(sm + (16 + lr) * 680 + kb * 32 + ko);
        bfrag bw = *(const bfrag*)(sm + 21760 + kb * 2048 + w * 512 + l * 8);
        acc0 = MFMA(a0, bw, acc0, 0, 0, 0);
        acc1 = MFMA(a1, bw, acc1, 0, 0, 0);
        if (kb < 16 && doy) {
          bfrag by = *(const bfrag*)(sm + 64768 + kb * 512 + l * 8);
          accy = MFMA(w == 0 ? a0 : a1, by, accy, 0, 0, 0);
        }
      }
      if (doy) {  // y_{t-1} raw -> d_out (MDN applied later in place)
        int gcol = m * 16 + lr;
        if (gcol < 123) {
          float bd = b_dec[gcol];
          int brow = B0 + h * 32 + w * 16 + (l >> 4) * 4;
          #pragma unroll
          for (int j = 0; j < 4; ++j)
            out[((size_t)(brow + j) * 256 + (t - 1)) * 123 + gcol] = accy[j] + bd;
        }
      }
      #pragma unroll
      for (int j = 0; j < 4; ++j) {
        gbuf[((l >> 4) * 4 + j) * 66 + w * 16 + lr] = acc0[j];
        gbuf[(16 + (l >> 4) * 4 + j) * 66 + w * 16 + lr] = acc1[j];
      }
      __syncthreads();
      #pragma unroll
      for (int p = 0; p < 2; ++p) {
        int idx = p * 256 + tid;
        int bl = idx >> 4, u = idx & 15;
        float gi = gbuf[bl * 66 + u * 4 + 0], gf = gbuf[bl * 66 + u * 4 + 1];
        float gg = gbuf[bl * 66 + u * 4 + 2], go = gbuf[bl * 66 + u * 4 + 3];
        float c = sigm(gf) * c_dec[h * 2 + p] + sigm(gi) * tanh_(gg);
        c_dec[h * 2 + p] = c;
        float hh = sigm(go) * tanh_(c);
        hdec[(size_t)(t & 1) * 262144 + (size_t)(B0 + h * 32 + bl) * 512 + m * 16 + u] = f2bf(hh);
      }
      gbar_arrive(flags, g, m, 517 + 2 * t + h, tid);
    }
  }
  // extra step: y_255 from h(255) (slot (255&1)=1)
  #pragma unroll
  for (int h = 0; h < 2; ++h) {
    gbar_wait(flags, g, 1027 + h, tid, &sdead);
    {
      const u16* src = hdec + 262144 + (size_t)(B0 + h * 32) * 512;
      #pragma unroll
      for (int i = 0; i < 8; ++i) {
        int c = i * 256 + tid;
        int row = c >> 6, col = (c & 63) * 8;
        *(bfrag*)(sm + row * 680 + col) = *(const bfrag*)(src + c * 8);
      }
    }
    __syncthreads();
    if ((m < 8) && w < 2) {
      f32x4 accy = {0.f, 0.f, 0.f, 0.f};
      #pragma unroll
      for (int kb = 0; kb < 16; ++kb) {
        bfrag a = *(const bfrag*)(sm + ((w ? 16 : 0) + lr) * 680 + kb * 32 + ko);
        bfrag by = *(const bfrag*)(sm + 64768 + kb * 512 + l * 8);
        accy = MFMA(a, by, accy, 0, 0, 0);
      }
      int gcol = m * 16 + lr;
      if (gcol < 123) {
        float bd = b_dec[gcol];
        int brow = B0 + h * 32 + w * 16 + (l >> 4) * 4;
        #pragma unroll
        for (int j = 0; j < 4; ++j)
          out[((size_t)(brow + j) * 256 + 255) * 123 + gcol] = accy[j] + bd;
      }
    }
    __syncthreads();
  }
}

// ============================================================= MDN in place
__global__ __launch_bounds__(64) void mdn_final(float* __restrict__ out) {
  __shared__ float rows[64 * 123];
  const int tid = threadIdx.x;
  float4* g4 = (float4*)(out + (size_t)blockIdx.x * 64 * 123);
  #pragma unroll
  for (int i = 0; i < 31; ++i) {
    int c = i * 64 + tid;
    if (c < 1968) ((float4*)rows)[c] = g4[c];
  }
  __syncthreads();
  {
    float* r = rows + tid * 123;
    float m1 = -1e30f;
    #pragma unroll
    for (int k = 0; k < 20; ++k) m1 = fmaxf(m1, r[6 * k]);
    float s1 = 0.f;
    #pragma unroll
    for (int k = 0; k < 20; ++k) s1 += __expf(r[6 * k] - m1);
    float i1 = 1.f / s1;
    #pragma unroll
    for (int k = 0; k < 20; ++k) {
      r[6 * k] = __expf(r[6 * k] - m1) * i1;
      r[6 * k + 3] = __expf(r[6 * k + 3]);
      r[6 * k + 4] = __expf(r[6 * k + 4]);
      r[6 * k + 5] = tanh_(r[6 * k + 5]);
    }
    float p0 = r[120], p1 = r[121], p2 = r[122];
    float mp = fmaxf(p0, fmaxf(p1, p2));
    float e0 = __expf(p0 - mp), e1 = __expf(p1 - mp), e2 = __expf(p2 - mp);
    float ip = 1.f / (e0 + e1 + e2);
    r[120] = e0 * ip; r[121] = e1 * ip; r[122] = e2 * ip;
  }
  __syncthreads();
  #pragma unroll
  for (int i = 0; i < 31; ++i) {
    int c = i * 64 + tid;
    if (c < 1968) g4[c] = ((float4*)rows)[c];
  }
}

extern "C" void kernel_launch(void* const* d_in, const int* in_sizes, int n_in,
                              void* d_out, int out_size, void* d_ws, size_t ws_size,
                              hipStream_t stream) {
  const float* s       = (const float*)d_in[0];
  const float* eps     = (const float*)d_in[1];
  const float* Wih_f   = (const float*)d_in[2];
  const float* Whh_f   = (const float*)d_in[3];
  const float* bih_f   = (const float*)d_in[4];
  const float* bhh_f   = (const float*)d_in[5];
  const float* Wih_b   = (const float*)d_in[6];
  const float* bih_b   = (const float*)d_in[8];
  const float* bhh_b   = (const float*)d_in[9];
  const float* W_sigma = (const float*)d_in[10];
  const float* b_sigma = (const float*)d_in[11];
  const float* W_mu    = (const float*)d_in[12];
  const float* b_mu    = (const float*)d_in[13];
  const float* W_h0    = (const float*)d_in[14];
  const float* b_h0    = (const float*)d_in[15];
  const float* Wih_d   = (const float*)d_in[16];
  const float* Whh_d   = (const float*)d_in[17];
  const float* bih_d   = (const float*)d_in[18];
  const float* bhh_d   = (const float*)d_in[19];
  const float* W_dec   = (const float*)d_in[20];
  const float* b_dec   = (const float*)d_in[21];

  char* ws = (char*)d_ws;
  int* FLAGS  = (int*)(ws + OFF_FLAGS);
  u16* HENC   = (u16*)(ws + OFF_HENC);
  u16* WENCP  = (u16*)(ws + OFF_WENC);
  u16* WDECP  = (u16*)(ws + OFF_WDEC);
  u16* WYP    = (u16*)(ws + OFF_WY);
  u16* WMSP   = (u16*)(ws + OFF_WMS);
  u16* WH0P   = (u16*)(ws + OFF_WH0);
  u16* HDEC   = (u16*)(ws + OFF_HDEC);
  u16* HLAT   = (u16*)(ws + OFF_HLAT);
  float* MS   = (float*)(ws + OFF_MS);
  u16* AZ     = (u16*)(ws + OFF_AZ);
  float* out  = (float*)d_out;

  // reset barrier flags + zero encoder h(-1) every launch (graph-replay safe)
  hipMemsetAsync(ws, 0, 4096 + 524288, stream);

  pack_wenc<<<1152, 256, 0, stream>>>(Whh_f, Wih_f, bih_f, bhh_f, WENCP);
  pack_wdec<<<5376, 256, 0, stream>>>(Whh_d, Wih_d, bih_d, bhh_d, WDECP);
  pack_wy<<<256, 256, 0, stream>>>(W_dec, WYP);
  pack_wms<<<544, 256, 0, stream>>>(W_mu, b_mu, W_sigma, b_sigma, WMSP);
  pack_wh0<<<320, 256, 0, stream>>>(W_h0, b_h0, WH0P);

  rnn_persist<<<256, 256, 0, stream>>>(FLAGS, HENC, WENCP, WDECP, WYP, WMSP, WH0P,
                                       HDEC, HLAT, MS, AZ, s, eps,
                                       Wih_b, bih_b, bhh_b, b_dec, out);

  mdn_final<<<2048, 64, 0, stream>>>(out);

  (void)in_sizes; (void)n_in; (void)out_size; (void)ws_size;
}

// Round 4
// 2983.623 us; speedup vs baseline: 6.2723x; 4.3000x over previous
//
#include <hip/hip_runtime.h>

typedef unsigned short u16;
typedef unsigned long long u64;
typedef __attribute__((ext_vector_type(8))) short bfrag;
typedef __attribute__((ext_vector_type(4))) float f32x4;

#define MFMA __builtin_amdgcn_mfma_f32_16x16x32_bf16

// ---------------- ws layout (bytes) ----------------
#define OFF_FLAGS 0ull           //  4096 (8 groups x 64 ints, 256B stride)
#define OFF_HENC  4096ull        //  524288 ([2][512][256] bf16)  <- memset w/ flags
#define OFF_WENC  528384ull      //  589824
#define OFF_WDEC  1118208ull     //  2752512
#define OFF_WY    3870720ull     //  131072
#define OFF_WMS   4001792ull     //  278528 ([256][544] bf16)
#define OFF_WH0   4280320ull     //  163840 ([512][160] bf16)
#define OFF_HDEC  4444160ull     //  1048576 ([2][512][512] bf16)
#define OFF_HLAT  5492736ull     //  557056 ([512][544] bf16)
#define OFF_MS    6049792ull     //  524288 ([512][256] f32)
#define OFF_AZ    6574080ull     //  163840 ([512][160] bf16)

__device__ __forceinline__ u16 f2bf(float f) {
  union { float f; unsigned int i; } v; v.f = f;
  unsigned int r = v.i + 0x7fffu + ((v.i >> 16) & 1u);
  return (u16)(r >> 16);
}
__device__ __forceinline__ float sigm(float x) { return 1.0f / (1.0f + __expf(-x)); }
__device__ __forceinline__ float tanh_(float x) {
  float a = fabsf(x);
  float e = __expf(-2.0f * a);
  float r = (1.0f - e) / (1.0f + e);
  return x < 0.0f ? -r : r;
}

// relaxed agent-scope (sc1) data movers: MALL-coherent, NO wbl2/inv fences
__device__ __forceinline__ u64 aload(const u64* p) {
  return __hip_atomic_load(p, __ATOMIC_RELAXED, __HIP_MEMORY_SCOPE_AGENT);
}
__device__ __forceinline__ void astore(u64* p, u64 v) {
  __hip_atomic_store(p, v, __ATOMIC_RELAXED, __HIP_MEMORY_SCOPE_AGENT);
}
__device__ __forceinline__ float afload(const float* p) {
  return __hip_atomic_load(p, __ATOMIC_RELAXED, __HIP_MEMORY_SCOPE_AGENT);
}
__device__ __forceinline__ void afstore(float* p, float v) {
  __hip_atomic_store(p, v, __ATOMIC_RELAXED, __HIP_MEMORY_SCOPE_AGENT);
}

// group barrier: 32 blocks of group g; relaxed polls, no fences.
__device__ __forceinline__ void gwait(int* flags, int g, int ep, int tid, int* sdead) {
  if (ep > 0) {
    if (tid < 32 && *sdead == 0) {
      int* fp = flags + g * 64 + tid;
      int spin = 0;
      while (__hip_atomic_load(fp, __ATOMIC_RELAXED, __HIP_MEMORY_SCOPE_AGENT) < ep) {
        __builtin_amdgcn_s_sleep(1);
        if (++spin > (1 << 20)) { *sdead = 1; break; }   // fail loud, never hang
      }
    }
  }
  __syncthreads();
  asm volatile("" ::: "memory");
}
__device__ __forceinline__ void garrive(int* flags, int g, int m, int ep, int tid) {
  asm volatile("s_waitcnt vmcnt(0)" ::: "memory");  // sc1 data stores ack'd at MALL
  __syncthreads();
  if (tid == 0)
    __hip_atomic_store(flags + g * 64 + m, ep, __ATOMIC_RELAXED, __HIP_MEMORY_SCOPE_AGENT);
}

// ============================================================= prep packs
__global__ void pack_wenc(const float* __restrict__ Whh, const float* __restrict__ Wih,
                          const float* __restrict__ bi, const float* __restrict__ bh,
                          u16* __restrict__ out) {
  int idx = blockIdx.x * 256 + threadIdx.x;
  if (idx >= 294912) return;
  int m = idx / 9216, within = idx % 9216;
  int kb = within >> 10, rest = within & 1023;
  int ng = rest >> 9, l = (rest >> 3) & 63, j = rest & 7;
  int nl = ng * 16 + (l & 15);
  int u = nl >> 2, g = nl & 3;
  int row = g * 256 + m * 8 + u;
  int k = kb * 32 + (l >> 4) * 8 + j;
  float v = 0.f;
  if (k < 256) v = Whh[row * 256 + k];
  else if (k < 261) v = Wih[row * 5 + (k - 256)];
  else if (k == 261) v = bi[row] + bh[row];
  out[idx] = f2bf(v);
}

__global__ void pack_wdec(const float* __restrict__ Whh, const float* __restrict__ Wih,
                          const float* __restrict__ bi, const float* __restrict__ bh,
                          u16* __restrict__ out) {
  int idx = blockIdx.x * 256 + threadIdx.x;
  if (idx >= 1376256) return;
  int m = idx / 43008, within = idx % 43008;
  int kb = within >> 11, rest = within & 2047;
  int w = rest >> 9, l = (rest >> 3) & 63, j = rest & 7;
  int nl = w * 16 + (l & 15);
  int u = nl >> 2, g = nl & 3;
  int row = g * 512 + m * 16 + u;
  int k = kb * 32 + (l >> 4) * 8 + j;
  float v = 0.f;
  if (k < 512) v = Whh[row * 512 + k];                    // h
  else if (k < 640) v = Wih[row * 133 + 5 + (k - 512)];   // z
  else if (k < 645) v = Wih[row * 133 + (k - 640)];       // x
  else if (k == 645) v = bi[row] + bh[row];
  out[idx] = f2bf(v);
}

__global__ void pack_wy(const float* __restrict__ Wd, u16* __restrict__ out) {
  int idx = blockIdx.x * 256 + threadIdx.x;
  if (idx >= 65536) return;
  int m = idx >> 13, within = idx & 8191;
  int kb = within >> 9, rest = within & 511;
  int l = rest >> 3, j = rest & 7;
  int row = m * 16 + (l & 15);
  int k = kb * 32 + (l >> 4) * 8 + j;
  float v = (row < 123 && k < 512) ? Wd[row * 512 + k] : 0.f;
  out[idx] = f2bf(v);
}

__global__ void pack_wms(const float* __restrict__ Wmu, const float* __restrict__ bmu,
                         const float* __restrict__ Wsig, const float* __restrict__ bsig,
                         u16* __restrict__ out) {
  int idx = blockIdx.x * 256 + threadIdx.x;
  if (idx >= 139264) return;
  int r = idx / 544, k = idx % 544;
  float v = 0.f;
  if (r < 128) {
    if (k < 512) v = Wmu[r * 512 + k];
    else if (k == 512) v = bmu[r];
  } else {
    int r2 = r - 128;
    if (k < 512) v = Wsig[r2 * 512 + k];
    else if (k == 512) v = bsig[r2];
  }
  out[idx] = f2bf(v);
}

__global__ void pack_wh0(const float* __restrict__ Wh0, const float* __restrict__ bh0,
                         u16* __restrict__ out) {
  int idx = blockIdx.x * 256 + threadIdx.x;
  if (idx >= 81920) return;
  int r = idx / 160, k = idx % 160;
  float v = 0.f;
  if (k < 128) v = Wh0[r * 128 + k];
  else if (k == 128) v = bh0[r];
  out[idx] = f2bf(v);
}

// ============================================================= persistent
// group g = blk & 7 (XCD-local), member m = blk >> 3. Group owns batch [g*64, g*64+64).
__global__ __launch_bounds__(256, 1) void rnn_persist(
    int* __restrict__ flags, u16* __restrict__ henc,
    const u16* __restrict__ WENCP, const u16* __restrict__ WDECP,
    const u16* __restrict__ WYP, const u16* __restrict__ WMSP, const u16* __restrict__ WH0P,
    u16* __restrict__ hdec, u16* __restrict__ hlat, float* __restrict__ msbuf,
    u16* __restrict__ Az,
    const float* __restrict__ s, const float* __restrict__ eps,
    const float* __restrict__ Wih_b, const float* __restrict__ bih_b,
    const float* __restrict__ bhh_b,
    const float* __restrict__ b_dec, float* __restrict__ out)
{
  // LDS: A-tile [32][680] u16 (43520B) | gate W (86016B) | y W (16384B)
  __shared__ __align__(16) u16 sm[72960];
  __shared__ __align__(16) float gbuf[2112];   // [32][66] f32 (latent scratch aliases this)
  __shared__ __align__(16) u16 hst[1024];      // h staging for packed stores
  __shared__ int sdead;

  const int tid = threadIdx.x;
  const int blk = blockIdx.x;
  const int g = blk & 7;
  const int m = blk >> 3;
  const int B0 = g * 64;
  const int w = tid >> 6, l = tid & 63;
  const int lr = l & 15, ko = (l >> 4) * 8;

  float* out_mu = out + 16121856;
  float* out_ps = out + 16187392;

  const int gcol = m * 16 + lr;
  float bd = 0.f;
  if (m < 8 && gcol < 123) bd = b_dec[gcol];

  if (tid == 0) sdead = 0;
  // zero encoder A region + set bias col
  {
    bfrag zz = {0, 0, 0, 0, 0, 0, 0, 0};
    #pragma unroll
    for (int i = 0; i < 5; ++i) {
      int c = i * 256 + tid;
      if (c < 1184) *(bfrag*)(sm + c * 8) = zz;   // 32*296 = 9472 u16 = 1184 frags
    }
  }
  // encoder weight slice -> LDS
  {
    const u16* src = WENCP + (size_t)m * 9216;
    #pragma unroll
    for (int i = 0; i < 5; ++i) {
      int c = i * 256 + tid;
      if (c < 1152) *(bfrag*)(sm + 21760 + c * 8) = *(const bfrag*)(src + c * 8);
    }
  }
  __syncthreads();
  if (tid < 32) sm[tid * 296 + 261] = 0x3F80;
  __syncthreads();

  // ---------------- encoder: 256 steps, 1 barrier/step, 2 serial halves ----------------
  float c_enc0 = 0.f, c_enc1 = 0.f;
  #pragma unroll 1
  for (int t = 0; t < 256; ++t) {
    gwait(flags, g, t, tid, &sdead);
    const u64* hs0 = (const u64*)(henc + (size_t)((t + 1) & 1) * 131072 + (size_t)B0 * 256);
    u64 hv0[8], hv1[8];
    #pragma unroll
    for (int i = 0; i < 8; ++i) hv0[i] = aload(hs0 + i * 256 + tid);
    #pragma unroll
    for (int i = 0; i < 8; ++i) hv1[i] = aload(hs0 + 2048 + i * 256 + tid);
    #pragma unroll
    for (int hh = 0; hh < 2; ++hh) {
      #pragma unroll
      for (int i = 0; i < 8; ++i) {
        int idx = i * 256 + tid;
        *(u64*)(sm + (idx >> 6) * 296 + (idx & 63) * 4) = (hh == 0) ? hv0[i] : hv1[i];
      }
      if (tid < 32) {
        const float* xr = s + ((size_t)(B0 + hh * 32 + tid) * 256 + t) * 5;
        #pragma unroll
        for (int j = 0; j < 5; ++j) sm[tid * 296 + 256 + j] = f2bf(xr[j]);
      }
      __syncthreads();
      const int mt = w >> 1, ng = w & 1;
      f32x4 acc = {0.f, 0.f, 0.f, 0.f};
      #pragma unroll
      for (int kb = 0; kb < 9; ++kb) {
        bfrag a = *(const bfrag*)(sm + (mt * 16 + lr) * 296 + kb * 32 + ko);
        bfrag bw = *(const bfrag*)(sm + 21760 + (kb * 2 + ng) * 512 + l * 8);
        acc = MFMA(a, bw, acc, 0, 0, 0);
      }
      #pragma unroll
      for (int j = 0; j < 4; ++j)
        gbuf[(mt * 16 + (l >> 4) * 4 + j) * 33 + ng * 16 + lr] = acc[j];
      __syncthreads();
      {
        int bl = tid >> 3, u = tid & 7;
        float gi = gbuf[bl * 33 + u * 4 + 0], gf = gbuf[bl * 33 + u * 4 + 1];
        float gg = gbuf[bl * 33 + u * 4 + 2], go = gbuf[bl * 33 + u * 4 + 3];
        float cprev = (hh == 0) ? c_enc0 : c_enc1;
        float c = sigm(gf) * cprev + sigm(gi) * tanh_(gg);
        if (hh == 0) c_enc0 = c; else c_enc1 = c;
        hst[bl * 8 + u] = f2bf(sigm(go) * tanh_(c));
      }
      __syncthreads();
      if (tid < 64) {
        int row = tid >> 1, q = tid & 1;
        u64 v = *(const u64*)(hst + row * 8 + q * 4);
        astore((u64*)(henc + (size_t)(t & 1) * 131072 + (size_t)(B0 + hh * 32 + row) * 256 + m * 8) + q, v);
      }
    }
    garrive(flags, g, m, t + 1, tid);
  }

  // ---------------- latent ----------------
  u16* lat_hf = (u16*)gbuf;          // [2][256]
  u16* lat_hb = (u16*)gbuf + 512;    // [2][256]
  u16* lat_z  = (u16*)gbuf + 1024;   // [2][128]

  gwait(flags, g, 256, tid, &sdead);
  {  // decoder gate weights -> LDS (overlaps latent math)
    const u16* src = WDECP + (size_t)m * 43008;
    #pragma unroll 1
    for (int i = 0; i < 21; ++i) {
      int c = i * 256 + tid;
      *(bfrag*)(sm + 21760 + c * 8) = *(const bfrag*)(src + c * 8);
    }
  }
  if (m < 8) {
    const u16* src = WYP + (size_t)m * 8192;
    #pragma unroll
    for (int i = 0; i < 4; ++i) {
      int c = i * 256 + tid;
      *(bfrag*)(sm + 64768 + c * 8) = *(const bfrag*)(src + c * 8);
    }
  }
  // Lphase A: backward-LSTM 1 step + hlat rows
  #pragma unroll
  for (int r = 0; r < 2; ++r) {
    int b = B0 + m * 2 + r;
    if (tid < 64) {
      u64 v = aload((const u64*)(henc + 131072 + (size_t)b * 256) + tid);
      *(u64*)(lat_hf + r * 256 + tid * 4) = v;
    }
    {
      const float* xr = s + ((size_t)b * 256 + 255) * 5;
      float x0 = xr[0], x1 = xr[1], x2 = xr[2], x3 = xr[3], x4 = xr[4];
      int n = tid;
      float gv[4];
      #pragma unroll
      for (int gg = 0; gg < 4; ++gg) {
        int row = gg * 256 + n;
        gv[gg] = bih_b[row] + bhh_b[row] + x0 * Wih_b[row * 5] + x1 * Wih_b[row * 5 + 1] +
                 x2 * Wih_b[row * 5 + 2] + x3 * Wih_b[row * 5 + 3] + x4 * Wih_b[row * 5 + 4];
      }
      float c = sigm(gv[0]) * tanh_(gv[2]);
      lat_hb[r * 256 + n] = f2bf(sigm(gv[3]) * tanh_(c));
    }
  }
  __syncthreads();
  #pragma unroll
  for (int it = 0; it < 2; ++it) {
    int idx = it * 256 + tid;
    if (idx < 272) {
      int rr = idx / 136, u = idx % 136;
      u64 pv = 0;
      #pragma unroll
      for (int q = 0; q < 4; ++q) {
        int c = u * 4 + q;
        u16 x;
        if (c < 256) x = lat_hf[rr * 256 + c];
        else if (c < 512) x = lat_hb[rr * 256 + c - 256];
        else if (c == 512) x = 0x3F80;
        else x = 0;
        pv |= ((u64)x) << (q * 16);
      }
      astore((u64*)(hlat + (size_t)(B0 + m * 2 + rr) * 544) + u, pv);
    }
  }
  garrive(flags, g, m, 257, tid);

  // Lphase B: [mu|presig] = hlat @ WMS^T
  gwait(flags, g, 257, tid, &sdead);
  {
    const int bH = m >> 4, cT = m & 15;
    const u64* src = (const u64*)(hlat + (size_t)(B0 + bH * 32) * 544);
    u64 sv[17];
    #pragma unroll
    for (int i = 0; i < 17; ++i) sv[i] = aload(src + i * 256 + tid);
    #pragma unroll
    for (int i = 0; i < 17; ++i) *(u64*)(sm + (i * 256 + tid) * 4) = sv[i];
    __syncthreads();
    if (w < 2) {
      f32x4 acc = {0.f, 0.f, 0.f, 0.f};
      const u16* bp = WMSP + (size_t)(cT * 16 + lr) * 544 + ko;
      #pragma unroll
      for (int kb = 0; kb < 17; ++kb) {
        bfrag a = *(const bfrag*)(sm + (w * 16 + lr) * 544 + kb * 32 + ko);
        bfrag bb = *(const bfrag*)(bp + kb * 32);
        acc = MFMA(a, bb, acc, 0, 0, 0);
      }
      int nc = cT * 16 + lr;
      #pragma unroll
      for (int j = 0; j < 4; ++j) {
        int b = B0 + bH * 32 + w * 16 + (l >> 4) * 4 + j;
        afstore(msbuf + (size_t)b * 256 + nc, acc[j]);
        if (nc < 128) out_mu[(size_t)b * 128 + nc] = acc[j];
        else out_ps[(size_t)b * 128 + nc - 128] = acc[j];
      }
    }
  }
  garrive(flags, g, m, 258, tid);

  // Lphase C: z = mu + exp(ps/2)*eps -> Az
  gwait(flags, g, 258, tid, &sdead);
  {
    int r = tid >> 7, zj = tid & 127;
    int b = B0 + m * 2 + r;
    float mu = afload(msbuf + (size_t)b * 256 + zj);
    float ps = afload(msbuf + (size_t)b * 256 + 128 + zj);
    float z = mu + __expf(0.5f * ps) * eps[zj];
    lat_z[r * 128 + zj] = f2bf(z);
  }
  __syncthreads();
  if (tid < 80) {
    int r = tid / 40, u = tid % 40;
    u64 pv = 0;
    #pragma unroll
    for (int q = 0; q < 4; ++q) {
      int c = u * 4 + q;
      u16 x;
      if (c < 128) x = lat_z[r * 128 + c];
      else if (c == 128) x = 0x3F80;
      else x = 0;
      pv |= ((u64)x) << (q * 16);
    }
    astore((u64*)(Az + (size_t)(B0 + m * 2 + r) * 160) + u, pv);
  }
  garrive(flags, g, m, 259, tid);

  // Lphase D: h0 = tanh(Az @ WH0^T); also pull z into regs for the decoder
  gwait(flags, g, 259, tid, &sdead);
  u64 zreg0[4], zreg1[4];
  {
    int r = tid >> 3;
    #pragma unroll
    for (int i = 0; i < 4; ++i) {
      int uu = (tid & 7) * 4 + i;
      zreg0[i] = aload((const u64*)(Az + (size_t)(B0 + r) * 160) + uu);
      zreg1[i] = aload((const u64*)(Az + (size_t)(B0 + 32 + r) * 160) + uu);
    }
  }
  {
    const u64* src = (const u64*)(Az + (size_t)B0 * 160);
    u64 sv[10];
    #pragma unroll
    for (int i = 0; i < 10; ++i) sv[i] = aload(src + i * 256 + tid);
    #pragma unroll
    for (int i = 0; i < 10; ++i) *(u64*)(sm + (i * 256 + tid) * 4) = sv[i];
    __syncthreads();
    f32x4 acc = {0.f, 0.f, 0.f, 0.f};
    const u16* bp = WH0P + (size_t)(m * 16 + lr) * 160 + ko;
    #pragma unroll
    for (int kb = 0; kb < 5; ++kb) {
      bfrag a = *(const bfrag*)(sm + (w * 16 + lr) * 160 + kb * 32 + ko);
      bfrag bb = *(const bfrag*)(bp + kb * 32);
      acc = MFMA(a, bb, acc, 0, 0, 0);
    }
    #pragma unroll
    for (int j = 0; j < 4; ++j)
      hst[(w * 16 + (l >> 4) * 4 + j) * 16 + lr] = f2bf(tanh_(acc[j]));
  }
  __syncthreads();
  // decoder A-tile constants: bias col 645 = 1, pads 646..679 = 0
  #pragma unroll
  for (int i = 0; i < 5; ++i) {
    int idx = i * 256 + tid;
    if (idx < 1120) {
      int row = idx / 35, c = idx % 35;
      sm[row * 680 + 645 + c] = (c == 0) ? 0x3F80 : 0;
    }
  }
  {
    int row = tid >> 2, q = tid & 3;
    u64 v = *(const u64*)(hst + row * 16 + q * 4);
    astore((u64*)(hdec + 262144 + (size_t)(B0 + row) * 512 + m * 16) + q, v);
  }
  garrive(flags, g, m, 260, tid);

  // ---------------- decoder: 256 steps, 1 barrier/step, fused y ----------------
  float c_dec00 = 0.f, c_dec01 = 0.f, c_dec10 = 0.f, c_dec11 = 0.f;
  #pragma unroll 1
  for (int t = 0; t < 256; ++t) {
    gwait(flags, g, 260 + t, tid, &sdead);
    const u64* hs0 = (const u64*)(hdec + (size_t)((t + 1) & 1) * 262144 + (size_t)B0 * 512);
    u64 hv0[16], hv1[16];
    #pragma unroll
    for (int i = 0; i < 16; ++i) hv0[i] = aload(hs0 + i * 256 + tid);
    #pragma unroll
    for (int i = 0; i < 16; ++i) hv1[i] = aload(hs0 + 4096 + i * 256 + tid);
    #pragma unroll
    for (int hh = 0; hh < 2; ++hh) {
      #pragma unroll
      for (int i = 0; i < 16; ++i) {
        int idx = i * 256 + tid;
        *(u64*)(sm + (idx >> 7) * 680 + (idx & 127) * 4) = (hh == 0) ? hv0[i] : hv1[i];
      }
      {
        int r = tid >> 3;
        #pragma unroll
        for (int i = 0; i < 4; ++i) {
          int uu = (tid & 7) * 4 + i;
          *(u64*)(sm + r * 680 + 512 + uu * 4) = (hh == 0) ? zreg0[i] : zreg1[i];
        }
      }
      if (tid < 32) {
        if (t == 0) {
          sm[tid * 680 + 640] = 0; sm[tid * 680 + 641] = 0; sm[tid * 680 + 642] = 0x3F80;
          sm[tid * 680 + 643] = 0; sm[tid * 680 + 644] = 0;
        } else {
          const float* xr = s + ((size_t)(B0 + hh * 32 + tid) * 256 + (t - 1)) * 5;
          #pragma unroll
          for (int j = 0; j < 5; ++j) sm[tid * 680 + 640 + j] = f2bf(xr[j]);
        }
      }
      __syncthreads();
      const int mtd = w & 1, nb = (w >> 1) * 2;
      const bool doy = (m < 8) && (w < 2) && (t > 0);
      f32x4 acc0 = {0.f, 0.f, 0.f, 0.f}, acc1 = {0.f, 0.f, 0.f, 0.f}, accy = {0.f, 0.f, 0.f, 0.f};
      #pragma unroll
      for (int kb = 0; kb < 21; ++kb) {
        bfrag a  = *(const bfrag*)(sm + (mtd * 16 + lr) * 680 + kb * 32 + ko);
        bfrag b0 = *(const bfrag*)(sm + 21760 + kb * 2048 + nb * 512 + l * 8);
        bfrag b1 = *(const bfrag*)(sm + 21760 + kb * 2048 + (nb + 1) * 512 + l * 8);
        acc0 = MFMA(a, b0, acc0, 0, 0, 0);
        acc1 = MFMA(a, b1, acc1, 0, 0, 0);
        if (kb < 16 && doy) {
          bfrag by = *(const bfrag*)(sm + 64768 + kb * 512 + l * 8);
          accy = MFMA(a, by, accy, 0, 0, 0);
        }
      }
      if (doy && gcol < 123) {
        int brow = B0 + hh * 32 + w * 16 + (l >> 4) * 4;
        #pragma unroll
        for (int j = 0; j < 4; ++j)
          out[((size_t)(brow + j) * 256 + (t - 1)) * 123 + gcol] = accy[j] + bd;
      }
      #pragma unroll
      for (int j = 0; j < 4; ++j) {
        int grow = mtd * 16 + (l >> 4) * 4 + j;
        gbuf[grow * 66 + nb * 16 + lr] = acc0[j];
        gbuf[grow * 66 + (nb + 1) * 16 + lr] = acc1[j];
      }
      __syncthreads();
      #pragma unroll
      for (int p = 0; p < 2; ++p) {
        int idx = p * 256 + tid;
        int bl = idx >> 4, u = idx & 15;
        float gi = gbuf[bl * 66 + u * 4 + 0], gf = gbuf[bl * 66 + u * 4 + 1];
        float gg = gbuf[bl * 66 + u * 4 + 2], go = gbuf[bl * 66 + u * 4 + 3];
        float cprev = (hh == 0) ? (p == 0 ? c_dec00 : c_dec01) : (p == 0 ? c_dec10 : c_dec11);
        float c = sigm(gf) * cprev + sigm(gi) * tanh_(gg);
        if (hh == 0) { if (p == 0) c_dec00 = c; else c_dec01 = c; }
        else         { if (p == 0) c_dec10 = c; else c_dec11 = c; }
        hst[bl * 16 + u] = f2bf(sigm(go) * tanh_(c));
      }
      __syncthreads();
      if (tid < 128) {
        int row = tid >> 2, q = tid & 3;
        u64 v = *(const u64*)(hst + row * 16 + q * 4);
        astore((u64*)(hdec + (size_t)(t & 1) * 262144 + (size_t)(B0 + hh * 32 + row) * 512 + m * 16) + q, v);
      }
    }
    garrive(flags, g, m, 261 + t, tid);
  }

  // extra epoch: y_255 from h(255) (slot 1)
  gwait(flags, g, 516, tid, &sdead);
  #pragma unroll
  for (int hh = 0; hh < 2; ++hh) {
    const u64* hsrc = (const u64*)(hdec + 262144 + (size_t)(B0 + hh * 32) * 512);
    u64 hv[16];
    #pragma unroll
    for (int i = 0; i < 16; ++i) hv[i] = aload(hsrc + i * 256 + tid);
    #pragma unroll
    for (int i = 0; i < 16; ++i) {
      int idx = i * 256 + tid;
      *(u64*)(sm + (idx >> 7) * 680 + (idx & 127) * 4) = hv[i];
    }
    __syncthreads();
    if (m < 8 && w < 2) {
      f32x4 accy = {0.f, 0.f, 0.f, 0.f};
      #pragma unroll
      for (int kb = 0; kb < 16; ++kb) {
        bfrag a = *(const bfrag*)(sm + (w * 16 + lr) * 680 + kb * 32 + ko);
        bfrag by = *(const bfrag*)(sm + 64768 + kb * 512 + l * 8);
        accy = MFMA(a, by, accy, 0, 0, 0);
      }
      if (gcol < 123) {
        int brow = B0 + hh * 32 + w * 16 + (l >> 4) * 4;
        #pragma unroll
        for (int j = 0; j < 4; ++j)
          out[((size_t)(brow + j) * 256 + 255) * 123 + gcol] = accy[j] + bd;
      }
    }
    __syncthreads();
  }
}

// ============================================================= MDN in place
__global__ __launch_bounds__(64) void mdn_final(float* __restrict__ out) {
  __shared__ float rows[64 * 123];
  const int tid = threadIdx.x;
  float4* g4 = (float4*)(out + (size_t)blockIdx.x * 64 * 123);
  #pragma unroll
  for (int i = 0; i < 31; ++i) {
    int c = i * 64 + tid;
    if (c < 1968) ((float4*)rows)[c] = g4[c];
  }
  __syncthreads();
  {
    float* r = rows + tid * 123;
    float m1 = -1e30f;
    #pragma unroll
    for (int k = 0; k < 20; ++k) m1 = fmaxf(m1, r[6 * k]);
    float s1 = 0.f;
    #pragma unroll
    for (int k = 0; k < 20; ++k) s1 += __expf(r[6 * k] - m1);
    float i1 = 1.f / s1;
    #pragma unroll
    for (int k = 0; k < 20; ++k) {
      r[6 * k] = __expf(r[6 * k] - m1) * i1;
      r[6 * k + 3] = __expf(r[6 * k + 3]);
      r[6 * k + 4] = __expf(r[6 * k + 4]);
      r[6 * k + 5] = tanh_(r[6 * k + 5]);
    }
    float p0 = r[120], p1 = r[121], p2 = r[122];
    float mp = fmaxf(p0, fmaxf(p1, p2));
    float e0 = __expf(p0 - mp), e1 = __expf(p1 - mp), e2 = __expf(p2 - mp);
    float ip = 1.f / (e0 + e1 + e2);
    r[120] = e0 * ip; r[121] = e1 * ip; r[122] = e2 * ip;
  }
  __syncthreads();
  #pragma unroll
  for (int i = 0; i < 31; ++i) {
    int c = i * 64 + tid;
    if (c < 1968) g4[c] = ((float4*)rows)[c];
  }
}

extern "C" void kernel_launch(void* const* d_in, const int* in_sizes, int n_in,
                              void* d_out, int out_size, void* d_ws, size_t ws_size,
                              hipStream_t stream) {
  const float* s       = (const float*)d_in[0];
  const float* eps     = (const float*)d_in[1];
  const float* Wih_f   = (const float*)d_in[2];
  const float* Whh_f   = (const float*)d_in[3];
  const float* bih_f   = (const float*)d_in[4];
  const float* bhh_f   = (const float*)d_in[5];
  const float* Wih_b   = (const float*)d_in[6];
  const float* bih_b   = (const float*)d_in[8];
  const float* bhh_b   = (const float*)d_in[9];
  const float* W_sigma = (const float*)d_in[10];
  const float* b_sigma = (const float*)d_in[11];
  const float* W_mu    = (const float*)d_in[12];
  const float* b_mu    = (const float*)d_in[13];
  const float* W_h0    = (const float*)d_in[14];
  const float* b_h0    = (const float*)d_in[15];
  const float* Wih_d   = (const float*)d_in[16];
  const float* Whh_d   = (const float*)d_in[17];
  const float* bih_d   = (const float*)d_in[18];
  const float* bhh_d   = (const float*)d_in[19];
  const float* W_dec   = (const float*)d_in[20];
  const float* b_dec   = (const float*)d_in[21];

  char* ws = (char*)d_ws;
  int* FLAGS  = (int*)(ws + OFF_FLAGS);
  u16* HENC   = (u16*)(ws + OFF_HENC);
  u16* WENCP  = (u16*)(ws + OFF_WENC);
  u16* WDECP  = (u16*)(ws + OFF_WDEC);
  u16* WYP    = (u16*)(ws + OFF_WY);
  u16* WMSP   = (u16*)(ws + OFF_WMS);
  u16* WH0P   = (u16*)(ws + OFF_WH0);
  u16* HDEC   = (u16*)(ws + OFF_HDEC);
  u16* HLAT   = (u16*)(ws + OFF_HLAT);
  float* MS   = (float*)(ws + OFF_MS);
  u16* AZ     = (u16*)(ws + OFF_AZ);
  float* out  = (float*)d_out;

  // reset barrier flags + zero encoder h(-1) every launch (graph-replay safe)
  hipMemsetAsync(ws, 0, 4096 + 524288, stream);

  pack_wenc<<<1152, 256, 0, stream>>>(Whh_f, Wih_f, bih_f, bhh_f, WENCP);
  pack_wdec<<<5376, 256, 0, stream>>>(Whh_d, Wih_d, bih_d, bhh_d, WDECP);
  pack_wy<<<256, 256, 0, stream>>>(W_dec, WYP);
  pack_wms<<<544, 256, 0, stream>>>(W_mu, b_mu, W_sigma, b_sigma, WMSP);
  pack_wh0<<<320, 256, 0, stream>>>(W_h0, b_h0, WH0P);

  rnn_persist<<<256, 256, 0, stream>>>(FLAGS, HENC, WENCP, WDECP, WYP, WMSP, WH0P,
                                       HDEC, HLAT, MS, AZ, s, eps,
                                       Wih_b, bih_b, bhh_b, b_dec, out);

  mdn_final<<<2048, 64, 0, stream>>>(out);

  (void)in_sizes; (void)n_in; (void)out_size; (void)ws_size;
}